// Round 9
// baseline (288.798 us; speedup 1.0000x reference)
//
#include <hip/hip_runtime.h>
#include <stdint.h>

typedef unsigned long long u64;

#define M_DIM 16384
#define N_DIM 2048
#define K_DIM 2048

// ---------------- fp4 MX-MFMA path ----------------
// C = x @ sign(w)^T, both operands {-1,+1}: exact in fp4 e2m1 (+1=0x2,
// -1=0xA); mfma_scale_f32_32x32x64_f8f6f4 with E8M0 scale 0x7F (=1.0) is
// exact, f32 accumulation of |sums|<=2048 exact -> absmax 0 (R8-verified).
//
// R9: R8's binding resource was the LDS pipe (128 KB/stage ~ 1540 cyc vs
// MFMA 1133). A-fragment regions are lane-linear -> load A STRAIGHT from
// L2 into VGPRs (full-stage register double-buffer, ~1133-cyc lookahead;
// unlike R4: co-scheduling kept, only the 2x-shared operand goes direct).
// B stays in LDS (shared by 4 waves; direct would 4x L2 traffic). LDS ->
// 80 KB/stage (~941 cyc) => MFMA-bound. Non-temporal C stores keep the
// per-XCD A(2MB)+B(2MB) working set L2-resident.

#define BM 256
#define BN 256
#define BK 128
#define NST (K_DIM / BK)           // 16 stages
// Region = 1 KB = one 32(m/n) x 64(k) fp4 tile; lane l holds row=l&31,
// k-half=l>>5, 16 B at region + l*16. A: [m_blk:64][stage:16][sub:2][t:8]
// regions; B: [n_blk:8][stage:16][sub:2][t:8]. All lane-linear ->
// coalesced loads/DMA, conflict-free ds_read_b128 (R2..R8: 0 conflicts).
// k/nibble permutations cancel (A,B packed identically).

typedef int   v4i  __attribute__((ext_vector_type(4)));
typedef int   v8i  __attribute__((ext_vector_type(8)));
typedef float v16f __attribute__((ext_vector_type(16)));

__device__ __forceinline__ void gld16(void* lds_base, const void* gsrc) {
    __builtin_amdgcn_global_load_lds(
        (const __attribute__((address_space(1))) uint32_t*)gsrc,
        (__attribute__((address_space(3))) uint32_t*)lds_base,
        16, 0, 0);
}

// Pack 8 floats -> 8 fp4 nibbles. e2m1: +1=0x2, -1=0xA (sign_fn: 0 -> +1).
__device__ __forceinline__ int pkn(float4 a, float4 b) {
    int r;
    r  = (a.x < 0.0f ? 0xA : 0x2);
    r |= (a.y < 0.0f ? 0xA : 0x2) << 4;
    r |= (a.z < 0.0f ? 0xA : 0x2) << 8;
    r |= (a.w < 0.0f ? 0xA : 0x2) << 12;
    r |= (b.x < 0.0f ? 0xA : 0x2) << 16;
    r |= (b.y < 0.0f ? 0xA : 0x2) << 20;
    r |= (b.z < 0.0f ? 0xA : 0x2) << 24;
    r |= (b.w < 0.0f ? 0xA : 0x2) << 28;
    return r;
}

// Merged pack: blocks [0,4096) pack x -> Ap (16384 regions); blocks
// [4096,4608) pack w -> Bp (2048 regions). One wave per region.
__global__ __launch_bounds__(256) void pack_fp4_all_kernel(
        const float* __restrict__ x, const float* __restrict__ w,
        char* __restrict__ Ap, char* __restrict__ Bp) {
    const int bid  = blockIdx.x;
    const bool isA = bid < 4096;
    const float* src = isA ? x : w;
    char*        dst = isA ? Ap : Bp;
    const int wid  = (isA ? bid : bid - 4096) * 4 + ((threadIdx.x >> 6) & 3);
    const int lane = threadIdx.x & 63;
    const int t    = wid & 7;
    const int sub  = (wid >> 3) & 1;
    const int st   = (wid >> 4) & 15;
    const int blk  = wid >> 8;
    const int row  = blk * 256 + t * 32 + (lane & 31);
    const int kb   = st * 128 + sub * 64 + (lane >> 5) * 32;
    const float4* p = (const float4*)(src + (size_t)row * K_DIM + kb);
    int4 o;
    o.x = pkn(p[0], p[1]);
    o.y = pkn(p[2], p[3]);
    o.z = pkn(p[4], p[5]);
    o.w = pkn(p[6], p[7]);
    *(int4*)(dst + (size_t)wid * 1024 + lane * 16) = o;
}

__device__ __forceinline__ v8i up8(v4i v) {
    v8i r;
    r[0] = v[0]; r[1] = v[1]; r[2] = v[2]; r[3] = v[3];
    r[4] = 0;    r[5] = 0;    r[6] = 0;    r[7] = 0;
    return r;
}

__global__ __launch_bounds__(512, 2) void bgemm_fp4_kernel(
        const char* __restrict__ Ap, const char* __restrict__ Bp,
        float* __restrict__ C) {
    // B-only double buffer: [buf:2][16 KB] = 32 KB.
    __shared__ __align__(16) char lds[2][16 * 1024];

    const int t    = threadIdx.x;
    const int lane = t & 63;
    const int wv   = t >> 6;                      // 0..7
    const int wm   = (wv >> 1) & 3;               // m-pair: 0..3
    const int wn   = wv & 1;                      // n-quad: 0..1

    // XCD swizzle (R4-proven): XCD x owns m_blks [8x,8x+8).
    const int id    = blockIdx.x;
    const int xcd   = id & 7;
    const int idx   = id >> 3;                    // 0..63
    const int m_blk = xcd * 8 + (idx & 7);        // 0..63
    const int n_blk = idx >> 3;                   // 0..7

    const char* aG = Ap + (size_t)m_blk * (NST * 16384) + lane * 16;
    const char* bG = Bp + (size_t)n_blk * (NST * 16384);

    v16f acc[2][4];
#pragma unroll
    for (int i = 0; i < 2; ++i)
#pragma unroll
        for (int j = 0; j < 4; ++j)
#pragma unroll
            for (int q = 0; q < 16; ++q) acc[i][j][q] = 0.0f;

    // B DMA: 16 regions/stage, 8 waves x 2 regions, lane-linear.
    auto dma = [&](int s, int buf) {
        const char* b = bG + (size_t)s * 16384;
#pragma unroll
        for (int r = 0; r < 2; ++r) {
            const int reg = wv * 2 + r;
            gld16(&lds[buf][reg * 1024], b + reg * 1024 + lane * 16);
        }
    };
    // A fragments direct from global (L2-resident slice), lane-linear.
    auto afload = [&](int s, v4i af[2][2]) {
        const char* a = aG + (size_t)s * 16384;
#pragma unroll
        for (int sub = 0; sub < 2; ++sub)
#pragma unroll
            for (int i = 0; i < 2; ++i)
                af[sub][i] = *(const v4i*)(a + (sub * 8 + wm * 2 + i) * 1024);
    };
    auto compute = [&](int buf, v4i af[2][2]) {
        const char* Bs = lds[buf];
#pragma unroll
        for (int sub = 0; sub < 2; ++sub) {
            v4i bf[4];
#pragma unroll
            for (int j = 0; j < 4; ++j)
                bf[j] = *(const v4i*)(Bs + (sub * 8 + wn * 4 + j) * 1024 + lane * 16);
#pragma unroll
            for (int i = 0; i < 2; ++i)
#pragma unroll
                for (int j = 0; j < 4; ++j)
                    acc[i][j] = __builtin_amdgcn_mfma_scale_f32_32x32x64_f8f6f4(
                        up8(af[sub][i]), up8(bf[j]), acc[i][j],
                        4, 4,                     // cbsz=fp4, blgp=fp4
                        0, 0x7F7F7F7F,            // A scale = 1.0
                        0, 0x7F7F7F7F);           // B scale = 1.0
        }
    };

    v4i af0[2][2], af1[2][2];
    dma(0, 0); afload(0, af0);
    __syncthreads();                       // prologue drain (once)
#pragma unroll 1
    for (int s = 0; s < NST; s += 2) {     // NST even
        dma(s + 1, 1); afload(s + 1, af1); // in flight during compute(s)
        compute(0, af0);
        __syncthreads();
        if (s + 2 < NST) { dma(s + 2, 0); afload(s + 2, af0); }
        compute(1, af1);
        __syncthreads();
    }

    // C/D layout (HW-measured, shape-determined):
    //   col = lane&31, row = (q&3) + 8*(q>>2) + 4*(lane>>5)
    // Non-temporal stores: keep A/B slices L2-resident.
    const int col = lane & 31;
    const int rq  = (lane >> 5) * 4;
#pragma unroll
    for (int i = 0; i < 2; ++i) {
#pragma unroll
        for (int j = 0; j < 4; ++j) {
            const int mbase = m_blk * BM + (wm * 2 + i) * 32;
            const int nbase = n_blk * BN + (wn * 4 + j) * 32;
#pragma unroll
            for (int q = 0; q < 16; ++q) {
                const int row = mbase + (q & 3) + 8 * (q >> 2) + rq;
                __builtin_nontemporal_store(
                    acc[i][j][q], &C[(size_t)row * N_DIM + nbase + col]);
            }
        }
    }
}

// ---------------- fallback: u64 XOR-popcount path (R1, known-good) ----------
#define KC 32
#define KT 16
struct alignas(16) u64x2 { u64 x, y; };

__global__ __launch_bounds__(256) void pack_sign_kernel(
        const float* __restrict__ in, u64* __restrict__ out, int ngroups) {
    int wid  = (blockIdx.x * 256 + threadIdx.x) >> 6;
    int lane = threadIdx.x & 63;
    if (wid >= ngroups) return;
    const float4* p = reinterpret_cast<const float4*>(in) + (size_t)wid * 64 + lane;
    float4 v = *p;
    u64 b0 = __ballot(v.x < 0.0f);
    u64 b1 = __ballot(v.y < 0.0f);
    u64 b2 = __ballot(v.z < 0.0f);
    u64 b3 = __ballot(v.w < 0.0f);
    if (lane == 0) {
        u64* o = out + (size_t)wid * 4;
        o[0] = b0; o[1] = b1; o[2] = b2; o[3] = b3;
    }
}

__global__ __launch_bounds__(256, 2) void bgemm_kernel(
        const u64* __restrict__ A, const u64* __restrict__ B,
        float* __restrict__ C) {
    __shared__ u64 As[KT][128];
    __shared__ u64 Bs[KT][128];
    const int t     = threadIdx.x;
    const int m_blk = blockIdx.y << 7;
    const int n_blk = blockIdx.x << 7;
    const int lane = t & 63;
    const int wave = t >> 6;
    const int tm   = lane >> 3;
    const int tn   = lane & 7;
    const int m0   = ((wave >> 1) << 6) + (tm << 3);
    const int n0   = ((wave & 1) << 6) + (tn << 3);
    unsigned acc[8][8];
#pragma unroll
    for (int i = 0; i < 8; ++i)
#pragma unroll
        for (int j = 0; j < 8; ++j) acc[i][j] = 0u;
    const int sr = t >> 3;
    const int sc = (t << 1) & 15;
    for (int ks = 0; ks < K_DIM / (KT * 64); ++ks) {
        const int cbase = ks * KT;
#pragma unroll
        for (int i = 0; i < 4; ++i) {
            int r = i * 32 + sr;
            u64x2 va = *reinterpret_cast<const u64x2*>(A + (size_t)(m_blk + r) * KC + cbase + sc);
            As[sc][r] = va.x; As[sc + 1][r] = va.y;
            u64x2 vb = *reinterpret_cast<const u64x2*>(B + (size_t)(n_blk + r) * KC + cbase + sc);
            Bs[sc][r] = vb.x; Bs[sc + 1][r] = vb.y;
        }
        __syncthreads();
#pragma unroll 1
        for (int c = 0; c < KT; ++c) {
            u64 a[8], b[8];
#pragma unroll
            for (int i = 0; i < 4; ++i) {
                u64x2 va = *reinterpret_cast<const u64x2*>(&As[c][m0 + 2 * i]);
                a[2 * i] = va.x; a[2 * i + 1] = va.y;
                u64x2 vb = *reinterpret_cast<const u64x2*>(&Bs[c][n0 + 2 * i]);
                b[2 * i] = vb.x; b[2 * i + 1] = vb.y;
            }
#pragma unroll
            for (int i = 0; i < 8; ++i)
#pragma unroll
                for (int j = 0; j < 8; ++j)
                    acc[i][j] += (unsigned)__builtin_popcountll(a[i] ^ b[j]);
        }
        __syncthreads();
    }
#pragma unroll
    for (int i = 0; i < 8; ++i) {
        float* o = C + (size_t)(m_blk + m0 + i) * N_DIM + n_blk + n0;
        float4 v0, v1;
        v0.x = (float)(K_DIM - 2 * (int)acc[i][0]);
        v0.y = (float)(K_DIM - 2 * (int)acc[i][1]);
        v0.z = (float)(K_DIM - 2 * (int)acc[i][2]);
        v0.w = (float)(K_DIM - 2 * (int)acc[i][3]);
        v1.x = (float)(K_DIM - 2 * (int)acc[i][4]);
        v1.y = (float)(K_DIM - 2 * (int)acc[i][5]);
        v1.z = (float)(K_DIM - 2 * (int)acc[i][6]);
        v1.w = (float)(K_DIM - 2 * (int)acc[i][7]);
        *reinterpret_cast<float4*>(o)     = v0;
        *reinterpret_cast<float4*>(o + 4) = v1;
    }
}

extern "C" void kernel_launch(void* const* d_in, const int* in_sizes, int n_in,
                              void* d_out, int out_size, void* d_ws, size_t ws_size,
                              hipStream_t stream) {
    const float* x = (const float*)d_in[0];
    const float* w = (const float*)d_in[1];
    float* out = (float*)d_out;

    const size_t needA = (size_t)M_DIM * K_DIM / 2;      // 16 MiB packed fp4 A
    const size_t needB = (size_t)N_DIM * K_DIM / 2;      // 2 MiB packed fp4 B
    if (ws_size >= needA + needB) {
        char* Ap = (char*)d_ws;
        char* Bp = Ap + needA;
        pack_fp4_all_kernel<<<4608, 256, 0, stream>>>(x, w, Ap, Bp);
        bgemm_fp4_kernel<<<(M_DIM / BM) * (N_DIM / BN), 512, 0, stream>>>(Ap, Bp, out);
    } else {
        u64* xb = (u64*)d_ws;
        u64* wb = xb + (size_t)M_DIM * KC;
        int xgroups = (M_DIM * K_DIM) / 256;
        int wgroups = (N_DIM * K_DIM) / 256;
        pack_sign_kernel<<<xgroups / 4, 256, 0, stream>>>(x, xb, xgroups);
        pack_sign_kernel<<<wgroups / 4, 256, 0, stream>>>(w, wb, wgroups);
        bgemm_kernel<<<dim3(N_DIM / 128, M_DIM / 128), 256, 0, stream>>>(xb, wb, out);
    }
}

// Round 10
// 283.642 us; speedup vs baseline: 1.0182x; 1.0182x over previous
//
#include <hip/hip_runtime.h>
#include <stdint.h>

typedef unsigned long long u64;

#define M_DIM 16384
#define N_DIM 2048
#define K_DIM 2048

// ---------------- fp4 MX-MFMA path ----------------
// C = x @ sign(w)^T, both operands {-1,+1}: exact in fp4 e2m1 (+1=0x2,
// -1=0xA); mfma_scale_f32_32x32x64_f8f6f4 with E8M0 scale 0x7F (=1.0) is
// exact, f32 accumulation of |sums|<=2048 exact -> absmax 0 (R8/R9 verified).
//
// R10 consolidation: R8's bgemm (A+B both LDS-staged; best measured, 286.3)
// + R9's merged single pack launch + R9's non-temporal C stores (keep the
// per-XCD A(2MB)+B(2MB) slices L2-resident). R9's A-direct was neutral ->
// dropped (adds per-wave L2 traffic + latency sensitivity for no gain).
// Session lessons baked in: acc <= 128 regs (R5 spill), 2 waves/SIMD (R5),
// per-stage cost is per-byte/LDS-pipe (R7), fp4 halves bytes + 2x rate (R8).

#define BM 256
#define BN 256
#define BK 128
#define NST (K_DIM / BK)           // 16 stages
// Region = 1 KB = one 32(m/n) x 64(k) fp4 tile; lane l holds row=l&31,
// k-half=l>>5, 16 B at region + l*16. A: [m_blk:64][stage:16][sub:2][t:8]
// regions; B: [n_blk:8][stage:16][sub:2][t:8]. All lane-linear ->
// coalesced loads/DMA, conflict-free ds_read_b128 (R2..R9: 0 conflicts).
// k/nibble permutations cancel (A,B packed identically).

typedef int   v4i  __attribute__((ext_vector_type(4)));
typedef int   v8i  __attribute__((ext_vector_type(8)));
typedef float v16f __attribute__((ext_vector_type(16)));

__device__ __forceinline__ void gld16(void* lds_base, const void* gsrc) {
    __builtin_amdgcn_global_load_lds(
        (const __attribute__((address_space(1))) uint32_t*)gsrc,
        (__attribute__((address_space(3))) uint32_t*)lds_base,
        16, 0, 0);
}

// Pack 8 floats -> 8 fp4 nibbles. e2m1: +1=0x2, -1=0xA (sign_fn: 0 -> +1).
__device__ __forceinline__ int pkn(float4 a, float4 b) {
    int r;
    r  = (a.x < 0.0f ? 0xA : 0x2);
    r |= (a.y < 0.0f ? 0xA : 0x2) << 4;
    r |= (a.z < 0.0f ? 0xA : 0x2) << 8;
    r |= (a.w < 0.0f ? 0xA : 0x2) << 12;
    r |= (b.x < 0.0f ? 0xA : 0x2) << 16;
    r |= (b.y < 0.0f ? 0xA : 0x2) << 20;
    r |= (b.z < 0.0f ? 0xA : 0x2) << 24;
    r |= (b.w < 0.0f ? 0xA : 0x2) << 28;
    return r;
}

// Merged pack: blocks [0,4096) pack x -> Ap (16384 regions); blocks
// [4096,4608) pack w -> Bp (2048 regions). One wave per region.
__global__ __launch_bounds__(256) void pack_fp4_all_kernel(
        const float* __restrict__ x, const float* __restrict__ w,
        char* __restrict__ Ap, char* __restrict__ Bp) {
    const int bid  = blockIdx.x;
    const bool isA = bid < 4096;
    const float* src = isA ? x : w;
    char*        dst = isA ? Ap : Bp;
    const int wid  = (isA ? bid : bid - 4096) * 4 + ((threadIdx.x >> 6) & 3);
    const int lane = threadIdx.x & 63;
    const int t    = wid & 7;
    const int sub  = (wid >> 3) & 1;
    const int st   = (wid >> 4) & 15;
    const int blk  = wid >> 8;
    const int row  = blk * 256 + t * 32 + (lane & 31);
    const int kb   = st * 128 + sub * 64 + (lane >> 5) * 32;
    const float4* p = (const float4*)(src + (size_t)row * K_DIM + kb);
    int4 o;
    o.x = pkn(p[0], p[1]);
    o.y = pkn(p[2], p[3]);
    o.z = pkn(p[4], p[5]);
    o.w = pkn(p[6], p[7]);
    *(int4*)(dst + (size_t)wid * 1024 + lane * 16) = o;
}

__device__ __forceinline__ v8i up8(v4i v) {
    // fp4 operand data lives in the low 4 of the 8 operand VGPRs.
    v8i r;
    r[0] = v[0]; r[1] = v[1]; r[2] = v[2]; r[3] = v[3];
    r[4] = 0;    r[5] = 0;    r[6] = 0;    r[7] = 0;
    return r;
}

__global__ __launch_bounds__(512, 2) void bgemm_fp4_kernel(
        const char* __restrict__ Ap, const char* __restrict__ Bp,
        float* __restrict__ C) {
    // Double-buffered stage: [buf:2][A 16 KB | B 16 KB] = 64 KB.
    __shared__ __align__(16) char lds[2][32 * 1024];

    const int t    = threadIdx.x;
    const int lane = t & 63;
    const int wv   = t >> 6;                      // 0..7
    const int wm   = (wv >> 1) & 3;               // m-pair: 0..3
    const int wn   = wv & 1;                      // n-quad: 0..1

    // XCD swizzle (R4-proven): XCD x owns m_blks [8x,8x+8).
    const int id    = blockIdx.x;
    const int xcd   = id & 7;
    const int idx   = id >> 3;                    // 0..63
    const int m_blk = xcd * 8 + (idx & 7);        // 0..63
    const int n_blk = idx >> 3;                   // 0..7

    const char* aG = Ap + (size_t)m_blk * (NST * 16384);
    const char* bG = Bp + (size_t)n_blk * (NST * 16384);

    v16f acc[2][4];
#pragma unroll
    for (int i = 0; i < 2; ++i)
#pragma unroll
        for (int j = 0; j < 4; ++j)
#pragma unroll
            for (int q = 0; q < 16; ++q) acc[i][j][q] = 0.0f;

    // 32 regions/stage (A:16 then B:16), 8 waves x 4 regions, lane-linear.
    auto dma = [&](int s, int buf) {
        const char* a = aG + (size_t)s * 16384;
        const char* b = bG + (size_t)s * 16384;
#pragma unroll
        for (int r = 0; r < 4; ++r) {
            const int reg = wv * 4 + r;
            const char* g = (reg < 16) ? (a + reg * 1024)
                                       : (b + (reg - 16) * 1024);
            gld16(&lds[buf][reg * 1024], g + lane * 16);
        }
    };

    auto compute = [&](int buf) {
        const char* As = lds[buf];
        const char* Bs = lds[buf] + 16384;
#pragma unroll
        for (int sub = 0; sub < 2; ++sub) {
            v8i af[2], bf[4];
#pragma unroll
            for (int i = 0; i < 2; ++i)
                af[i] = up8(*(const v4i*)(As + (sub * 8 + wm * 2 + i) * 1024 + lane * 16));
#pragma unroll
            for (int j = 0; j < 4; ++j)
                bf[j] = up8(*(const v4i*)(Bs + (sub * 8 + wn * 4 + j) * 1024 + lane * 16));
#pragma unroll
            for (int i = 0; i < 2; ++i)
#pragma unroll
                for (int j = 0; j < 4; ++j)
                    acc[i][j] = __builtin_amdgcn_mfma_scale_f32_32x32x64_f8f6f4(
                        af[i], bf[j], acc[i][j],
                        4, 4,                     // cbsz=fp4, blgp=fp4
                        0, 0x7F7F7F7F,            // A scale = 1.0 (E8M0 127)
                        0, 0x7F7F7F7F);           // B scale = 1.0
        }
    };

    dma(0, 0);
    __syncthreads();                       // prologue drain (once)
#pragma unroll 1
    for (int s = 0; s < NST; ++s) {
        if (s + 1 < NST) dma(s + 1, (s + 1) & 1);
        compute(s & 1);                    // ~1133 cyc/SIMD, DMA in flight
        __syncthreads();
    }

    // C/D layout (HW-measured, shape-determined):
    //   col = lane&31, row = (q&3) + 8*(q>>2) + 4*(lane>>5)
    // Non-temporal stores: don't evict the L2-resident A/B slices.
    const int col = lane & 31;
    const int rq  = (lane >> 5) * 4;
#pragma unroll
    for (int i = 0; i < 2; ++i) {
#pragma unroll
        for (int j = 0; j < 4; ++j) {
            const int mbase = m_blk * BM + (wm * 2 + i) * 32;
            const int nbase = n_blk * BN + (wn * 4 + j) * 32;
#pragma unroll
            for (int q = 0; q < 16; ++q) {
                const int row = mbase + (q & 3) + 8 * (q >> 2) + rq;
                __builtin_nontemporal_store(
                    acc[i][j][q], &C[(size_t)row * N_DIM + nbase + col]);
            }
        }
    }
}

// ---------------- fallback: u64 XOR-popcount path (R1, known-good) ----------
#define KC 32
#define KT 16
struct alignas(16) u64x2 { u64 x, y; };

__global__ __launch_bounds__(256) void pack_sign_kernel(
        const float* __restrict__ in, u64* __restrict__ out, int ngroups) {
    int wid  = (blockIdx.x * 256 + threadIdx.x) >> 6;
    int lane = threadIdx.x & 63;
    if (wid >= ngroups) return;
    const float4* p = reinterpret_cast<const float4*>(in) + (size_t)wid * 64 + lane;
    float4 v = *p;
    u64 b0 = __ballot(v.x < 0.0f);
    u64 b1 = __ballot(v.y < 0.0f);
    u64 b2 = __ballot(v.z < 0.0f);
    u64 b3 = __ballot(v.w < 0.0f);
    if (lane == 0) {
        u64* o = out + (size_t)wid * 4;
        o[0] = b0; o[1] = b1; o[2] = b2; o[3] = b3;
    }
}

__global__ __launch_bounds__(256, 2) void bgemm_kernel(
        const u64* __restrict__ A, const u64* __restrict__ B,
        float* __restrict__ C) {
    __shared__ u64 As[KT][128];
    __shared__ u64 Bs[KT][128];
    const int t     = threadIdx.x;
    const int m_blk = blockIdx.y << 7;
    const int n_blk = blockIdx.x << 7;
    const int lane = t & 63;
    const int wave = t >> 6;
    const int tm   = lane >> 3;
    const int tn   = lane & 7;
    const int m0   = ((wave >> 1) << 6) + (tm << 3);
    const int n0   = ((wave & 1) << 6) + (tn << 3);
    unsigned acc[8][8];
#pragma unroll
    for (int i = 0; i < 8; ++i)
#pragma unroll
        for (int j = 0; j < 8; ++j) acc[i][j] = 0u;
    const int sr = t >> 3;
    const int sc = (t << 1) & 15;
    for (int ks = 0; ks < K_DIM / (KT * 64); ++ks) {
        const int cbase = ks * KT;
#pragma unroll
        for (int i = 0; i < 4; ++i) {
            int r = i * 32 + sr;
            u64x2 va = *reinterpret_cast<const u64x2*>(A + (size_t)(m_blk + r) * KC + cbase + sc);
            As[sc][r] = va.x; As[sc + 1][r] = va.y;
            u64x2 vb = *reinterpret_cast<const u64x2*>(B + (size_t)(n_blk + r) * KC + cbase + sc);
            Bs[sc][r] = vb.x; Bs[sc + 1][r] = vb.y;
        }
        __syncthreads();
#pragma unroll 1
        for (int c = 0; c < KT; ++c) {
            u64 a[8], b[8];
#pragma unroll
            for (int i = 0; i < 4; ++i) {
                u64x2 va = *reinterpret_cast<const u64x2*>(&As[c][m0 + 2 * i]);
                a[2 * i] = va.x; a[2 * i + 1] = va.y;
                u64x2 vb = *reinterpret_cast<const u64x2*>(&Bs[c][n0 + 2 * i]);
                b[2 * i] = vb.x; b[2 * i + 1] = vb.y;
            }
#pragma unroll
            for (int i = 0; i < 8; ++i)
#pragma unroll
                for (int j = 0; j < 8; ++j)
                    acc[i][j] += (unsigned)__builtin_popcountll(a[i] ^ b[j]);
        }
        __syncthreads();
    }
#pragma unroll
    for (int i = 0; i < 8; ++i) {
        float* o = C + (size_t)(m_blk + m0 + i) * N_DIM + n_blk + n0;
        float4 v0, v1;
        v0.x = (float)(K_DIM - 2 * (int)acc[i][0]);
        v0.y = (float)(K_DIM - 2 * (int)acc[i][1]);
        v0.z = (float)(K_DIM - 2 * (int)acc[i][2]);
        v0.w = (float)(K_DIM - 2 * (int)acc[i][3]);
        v1.x = (float)(K_DIM - 2 * (int)acc[i][4]);
        v1.y = (float)(K_DIM - 2 * (int)acc[i][5]);
        v1.z = (float)(K_DIM - 2 * (int)acc[i][6]);
        v1.w = (float)(K_DIM - 2 * (int)acc[i][7]);
        *reinterpret_cast<float4*>(o)     = v0;
        *reinterpret_cast<float4*>(o + 4) = v1;
    }
}

extern "C" void kernel_launch(void* const* d_in, const int* in_sizes, int n_in,
                              void* d_out, int out_size, void* d_ws, size_t ws_size,
                              hipStream_t stream) {
    const float* x = (const float*)d_in[0];
    const float* w = (const float*)d_in[1];
    float* out = (float*)d_out;

    const size_t needA = (size_t)M_DIM * K_DIM / 2;      // 16 MiB packed fp4 A
    const size_t needB = (size_t)N_DIM * K_DIM / 2;      // 2 MiB packed fp4 B
    if (ws_size >= needA + needB) {
        char* Ap = (char*)d_ws;
        char* Bp = Ap + needA;
        pack_fp4_all_kernel<<<4608, 256, 0, stream>>>(x, w, Ap, Bp);
        bgemm_fp4_kernel<<<(M_DIM / BM) * (N_DIM / BN), 512, 0, stream>>>(Ap, Bp, out);
    } else {
        u64* xb = (u64*)d_ws;
        u64* wb = xb + (size_t)M_DIM * KC;
        int xgroups = (M_DIM * K_DIM) / 256;
        int wgroups = (N_DIM * K_DIM) / 256;
        pack_sign_kernel<<<xgroups / 4, 256, 0, stream>>>(x, xb, xgroups);
        pack_sign_kernel<<<wgroups / 4, 256, 0, stream>>>(w, wb, wgroups);
        bgemm_kernel<<<dim3(N_DIM / 128, M_DIM / 128), 256, 0, stream>>>(xb, wb, out);
    }
}